// Round 13
// baseline (68.285 us; speedup 1.0000x reference)
//
#include <hip/hip_runtime.h>
#include <math.h>

#define CDIM 1024
#define RDIM 100
#define NBAGS 8192
#define RPAD 112            // 7 r-tiles of 16
#define BPB 16              // bags per block
#define NBLK (NBAGS / BPB)  // 512

typedef float floatx4 __attribute__((ext_vector_type(4)));
typedef short bf16x8 __attribute__((ext_vector_type(8)));

__device__ __forceinline__ float dot4(float4 a, float4 b) {
    return a.x * b.x + a.y * b.y + a.z * b.z + a.w * b.w;
}

// fp32 -> bf16 round-to-nearest-even
__device__ __forceinline__ unsigned short f2bf(float f) {
    unsigned int u = __builtin_bit_cast(unsigned int, f);
    u += 0x7FFFu + ((u >> 16) & 1u);
    return (unsigned short)(u >> 16);
}

#define LOADROW(D0, D1, D2, D3, ri)                                          \
    {                                                                        \
        const float4* p_ = (const float4*)(X + (size_t)(ri) * CDIM);         \
        D0 = p_[lane];       D1 = p_[lane + 64];                             \
        D2 = p_[lane + 128]; D3 = p_[lane + 192];                            \
    }

// Online-softmax update with one row held in named registers.
#define COMPUTE_ROW(A0, A1, A2, A3)                                          \
    {                                                                        \
        float p = dot4(A0, c0) + dot4(A1, c1) + dot4(A2, c2) + dot4(A3, c3); \
        p += __shfl_xor(p, 1);                                               \
        p += __shfl_xor(p, 2);                                               \
        p += __shfl_xor(p, 4);                                               \
        p += __shfl_xor(p, 8);                                               \
        p += __shfl_xor(p, 16);                                              \
        p += __shfl_xor(p, 32);                                              \
        const float newm = fmaxf(m, p);                                      \
        const float corr = __expf(m - newm);  /* 0 on first row */           \
        const float wgt  = __expf(p - newm);                                 \
        denom = fmaf(denom, corr, wgt);                                      \
        a0.x = fmaf(a0.x, corr, wgt * A0.x); a0.y = fmaf(a0.y, corr, wgt * A0.y); \
        a0.z = fmaf(a0.z, corr, wgt * A0.z); a0.w = fmaf(a0.w, corr, wgt * A0.w); \
        a1.x = fmaf(a1.x, corr, wgt * A1.x); a1.y = fmaf(a1.y, corr, wgt * A1.y); \
        a1.z = fmaf(a1.z, corr, wgt * A1.z); a1.w = fmaf(a1.w, corr, wgt * A1.w); \
        a2.x = fmaf(a2.x, corr, wgt * A2.x); a2.y = fmaf(a2.y, corr, wgt * A2.y); \
        a2.z = fmaf(a2.z, corr, wgt * A2.z); a2.w = fmaf(a2.w, corr, wgt * A2.w); \
        a3.x = fmaf(a3.x, corr, wgt * A3.x); a3.y = fmaf(a3.y, corr, wgt * A3.y); \
        a3.z = fmaf(a3.z, corr, wgt * A3.z); a3.w = fmaf(a3.w, corr, wgt * A3.w); \
        m = newm;                                                            \
    }

// Prep kernel: build PW (W in B-fragment order, bf16, zero-padded rows
// 100..111). PW[((kc*7+t)*64 + lane)*8 + i] = W[t*16+(lane&15)][kc*32+(lane>>4)*8+i]
__global__ __launch_bounds__(256) void pw_prep(
    const float* __restrict__ W, unsigned short* __restrict__ PW)
{
    const int rr = blockIdx.x;          // 0..111
    const int t  = threadIdx.x;         // channels c = 4t..4t+3
    const int kc  = t >> 3;
    const int sub = (t >> 1) & 3;
    const int i0  = (t & 1) * 4;
    ushort4 o = {0, 0, 0, 0};
    if (rr < RDIM) {
        float4 v = *(const float4*)(W + (size_t)rr * CDIM + t * 4);
        o.x = f2bf(v.x); o.y = f2bf(v.y); o.z = f2bf(v.z); o.w = f2bf(v.w);
    }
    const int tt = rr >> 4, rl = rr & 15;
    *(ushort4*)(PW + ((size_t)(kc * 7 + tt) * 64 + sub * 16 + rl) * 8 + i0) = o;
}

// Fused kernel: block = 16 consecutive bags, 4 waves.
// Phase 1 (per bag): rows striped across waves, per-wave online-softmax state
// in registers, 2-deep prefetch, LDS merge -> bf16 bag vector into SWIZZLED
// LDS tile bagsm[16][1024] (never touches HBM). Next bag's Constraints are
// prefetched before the merge syncs to hide their latency.
// Phase 2: wave w MFMAs r-tiles {w, w+4} over full K from LDS (A, swizzled
// ds_read_b128, 2-way conflict = free) x packed PW (B, 1KB coalesced L2-hot),
// writes out directly. No K-split reduce, no second GEMM launch, no A-gather.
__global__ __launch_bounds__(256) void fused_kernel(
    const float* __restrict__ X,
    const float* __restrict__ Constraints,
    const int* __restrict__ scope,
    const int* __restrict__ rel,
    const unsigned short* __restrict__ PW,
    const float* __restrict__ bias,
    float* __restrict__ out)
{
    __shared__ float4 mergebuf[4][256];                 // 16 KB
    __shared__ float  lds_m[4];
    __shared__ float  lds_d[4];
    __shared__ unsigned short bagsm[BPB][CDIM];         // 32 KB, swizzled

    const int lane = threadIdx.x & 63;
    const int w    = threadIdx.x >> 6;
    const int t    = threadIdx.x;
    const int bag0 = blockIdx.x * BPB;

    // constraints for bag 0 of this block
    float4 c0, c1, c2, c3;
    {
        const float4* conp = (const float4*)(Constraints + (size_t)rel[bag0] * CDIM);
        c0 = conp[lane]; c1 = conp[lane + 64]; c2 = conp[lane + 128]; c3 = conp[lane + 192];
    }

    #pragma unroll 1
    for (int j = 0; j < BPB; ++j) {
        const int bag = bag0 + j;
        const int s = scope[2 * bag];
        const int e = scope[2 * bag + 1];

        float4 a0 = {0.f, 0.f, 0.f, 0.f};
        float4 a1 = {0.f, 0.f, 0.f, 0.f};
        float4 a2 = {0.f, 0.f, 0.f, 0.f};
        float4 a3 = {0.f, 0.f, 0.f, 0.f};
        float m = -INFINITY;
        float denom = 0.f;

        int row = s + w;
        if (row < e) {                    // uniform per wave
            float4 A0, A1, A2, A3;        // row
            float4 B0, B1, B2, B3;        // row+4
            float4 C0, C1, C2, C3;        // row+8 (rotating)

            LOADROW(A0, A1, A2, A3, row)
            if (row + 4 < e) LOADROW(B0, B1, B2, B3, row + 4)

            for (; row + 8 < e; row += 4) {
                LOADROW(C0, C1, C2, C3, row + 8)
                __builtin_amdgcn_sched_barrier(0);
                COMPUTE_ROW(A0, A1, A2, A3)
                A0 = B0; A1 = B1; A2 = B2; A3 = B3;
                B0 = C0; B1 = C1; B2 = C2; B3 = C3;
            }
            if (row + 4 < e) {
                COMPUTE_ROW(A0, A1, A2, A3)
                COMPUTE_ROW(B0, B1, B2, B3)
            } else {
                COMPUTE_ROW(A0, A1, A2, A3)
            }
        }

        // prefetch next bag's constraints (independent of the merge below)
        float4 n0, n1, n2, n3;
        if (j + 1 < BPB) {
            const float4* conp = (const float4*)(Constraints + (size_t)rel[bag + 1] * CDIM);
            n0 = conp[lane]; n1 = conp[lane + 64]; n2 = conp[lane + 128]; n3 = conp[lane + 192];
        }

        if (lane == 0) { lds_m[w] = m; lds_d[w] = denom; }
        mergebuf[w][lane]       = a0;
        mergebuf[w][lane + 64]  = a1;
        mergebuf[w][lane + 128] = a2;
        mergebuf[w][lane + 192] = a3;
        __syncthreads();

        const float m0 = lds_m[0], m1 = lds_m[1], m2 = lds_m[2], m3 = lds_m[3];
        const float ms = fmaxf(fmaxf(m0, m1), fmaxf(m2, m3));
        const float f0 = __expf(m0 - ms);   // idle wave: exp(-inf) = 0
        const float f1 = __expf(m1 - ms);
        const float f2 = __expf(m2 - ms);
        const float f3 = __expf(m3 - ms);
        const float dn = f0 * lds_d[0] + f1 * lds_d[1] + f2 * lds_d[2] + f3 * lds_d[3];
        const float inv = 1.0f / dn;

        const float4 v0 = mergebuf[0][t];
        const float4 v1 = mergebuf[1][t];
        const float4 v2 = mergebuf[2][t];
        const float4 v3 = mergebuf[3][t];
        const float ox = (f0 * v0.x + f1 * v1.x + f2 * v2.x + f3 * v3.x) * inv;
        const float oy = (f0 * v0.y + f1 * v1.y + f2 * v2.y + f3 * v3.y) * inv;
        const float oz = (f0 * v0.z + f1 * v1.z + f2 * v2.z + f3 * v3.z) * inv;
        const float ow = (f0 * v0.w + f1 * v1.w + f2 * v2.w + f3 * v3.w) * inv;

        ushort4 o;
        o.x = f2bf(ox); o.y = f2bf(oy); o.z = f2bf(oz); o.w = f2bf(ow);
        // swizzled LDS store: channels 4t..4t+3 -> 16B block (t>>1) ^ (j&7)
        const int blk = (t >> 1) ^ (j & 7);
        *(ushort4*)((char*)&bagsm[j][0] + blk * 16 + (t & 1) * 8) = o;
        __syncthreads();   // mergebuf reuse + (after last bag) bagsm complete

        c0 = n0; c1 = n1; c2 = n2; c3 = n3;
    }

    // ---- Phase 2: GEMM from LDS, full K per wave, tiles {w, w+4} ----
    const int ln15 = lane & 15;
    const int kgrp = lane >> 4;          // 0..3
    const int tA = w, tB = w + 4;        // tB valid if < 7
    floatx4 accA = (floatx4){0.f, 0.f, 0.f, 0.f};
    floatx4 accB = (floatx4){0.f, 0.f, 0.f, 0.f};
    const bool hasB = (tB < 7);

    #pragma unroll 4
    for (int kc = 0; kc < CDIM / 32; ++kc) {
        // A-frag: lane holds bagsm[ln15][kc*32 + kgrp*8 .. +8] (swizzled)
        const int swz = (kc * 4 + kgrp) ^ (ln15 & 7);
        const bf16x8 a = *(const bf16x8*)((const char*)&bagsm[ln15][0] + swz * 16);
        const bf16x8 bA = *(const bf16x8*)(PW + ((size_t)(kc * 7 + tA) * 64 + lane) * 8);
        accA = __builtin_amdgcn_mfma_f32_16x16x32_bf16(a, bA, accA, 0, 0, 0);
        if (hasB) {
            const bf16x8 bB = *(const bf16x8*)(PW + ((size_t)(kc * 7 + tB) * 64 + lane) * 8);
            accB = __builtin_amdgcn_mfma_f32_16x16x32_bf16(a, bB, accB, 0, 0, 0);
        }
    }

    // epilogue: D col = lane&15 (r within tile), row = (lane>>4)*4 + reg (bag)
    const int mbase = kgrp * 4;
    {
        const int r = tA * 16 + ln15;
        if (r < RDIM) {
            const float bv = bias[r];
            #pragma unroll
            for (int reg = 0; reg < 4; ++reg)
                out[(size_t)(bag0 + mbase + reg) * RDIM + r] = accA[reg] + bv;
        }
    }
    if (hasB) {
        const int r = tB * 16 + ln15;
        if (r < RDIM) {
            const float bv = bias[r];
            #pragma unroll
            for (int reg = 0; reg < 4; ++reg)
                out[(size_t)(bag0 + mbase + reg) * RDIM + r] = accB[reg] + bv;
        }
    }
}

extern "C" void kernel_launch(void* const* d_in, const int* in_sizes, int n_in,
                              void* d_out, int out_size, void* d_ws, size_t ws_size,
                              hipStream_t stream) {
    const float* X    = (const float*)d_in[0];
    const float* Con  = (const float*)d_in[1];
    const float* W    = (const float*)d_in[2];
    const float* bias = (const float*)d_in[3];
    const int* scope  = (const int*)d_in[4];
    const int* rel    = (const int*)d_in[5];
    float* out = (float*)d_out;

    unsigned short* PW = (unsigned short*)d_ws;   // 112*1024*2 = 0.23 MB

    pw_prep<<<RPAD, 256, 0, stream>>>(W, PW);
    fused_kernel<<<NBLK, 256, 0, stream>>>(X, Con, scope, rel, PW, bias, out);
}